// Round 4
// baseline (322.178 us; speedup 1.0000x reference)
//
#include <hip/hip_runtime.h>
#include <math.h>

#define QSEQ 33600

typedef __attribute__((ext_vector_type(8))) short short8;
typedef __attribute__((ext_vector_type(4))) float floatx4;
typedef unsigned short ushort_t;

static __device__ __forceinline__ ushort_t f2bf(float f) {
  unsigned u = __float_as_uint(f);
  return (ushort_t)((u + 0x7FFF + ((u >> 16) & 1)) >> 16);
}

// packed f32x2 -> bf16x2 (RNE, same rounding as f2bf), single VALU op
static __device__ __forceinline__ unsigned pk2bf(float lo, float hi) {
  unsigned r;
  asm("v_cvt_pk_bf16_f32 %0, %1, %2" : "=v"(r) : "v"(lo), "v"(hi));
  return r;
}

static __device__ __forceinline__ short8 cvt8(const float4 x0, const float4 x1) {
  union { unsigned u[4]; short8 s; } r;
  r.u[0] = pk2bf(x0.x, x0.y);
  r.u[1] = pk2bf(x0.z, x0.w);
  r.u[2] = pk2bf(x1.x, x1.y);
  r.u[3] = pk2bf(x1.z, x1.w);
  return r.s;
}

static __device__ __forceinline__ float4 add4(float4 a, const float4 b) {
  a.x += b.x; a.y += b.y; a.z += b.z; a.w += b.w;
  return a;
}

// ---------------------------------------------------------------------------
// MFMA GEMM body v2 (round 9): BARRIER-FREE K-loop.
//   BM=96, BN=128, K=256 whole. 256 thr = 4 waves (2x2), wave tile 48x64.
//   - B (weights, L2-hot) staged ONCE into LDS as bf16 [128 rows][32 chunks
//     of 8 elems], chunk-XOR swizzle slot = kc ^ (row&7). 64 KB, one barrier.
//   - A fragments loaded DIRECTLY global->VGPR per k32 step (lane (l16,quad)
//     reads A[row][k32*32+quad*8 ..+8] = 16 rows x 64B full cache lines),
//     cvt via v_cvt_pk_bf16_f32. No LDS for A, no K-loop barriers: waves run
//     independently and hide each other's latency (round-3 counters showed
//     the barrier-coupled chain stalled 85% of cycles: MfmaUtil 5.7%).
// ASRC: 0 = A bf16 direct; 1 = A fp32 cvt; 2 = fp32 A1+A2 add.
// MODE: 0 = fp32 C1[M,N]; 1 = bf16 head-major [col>>5][row][col&31];
//       2 = N=288 merged: cols<96 logits -> fused softmax -> C1 [Q,96] fp32,
//           cols [96,288) -> C2 [Q,192] fp32 (+b2).
// ---------------------------------------------------------------------------
template <int ASRC, int MODE>
static __device__ __forceinline__ void gemm_body(
    const int bx, const int by,
    const float* __restrict__ A1, const float* __restrict__ A2,
    const ushort_t* __restrict__ Ab,
    const float* __restrict__ B1, const float* __restrict__ B2, const int bsplit,
    const float* __restrict__ b1, const float* __restrict__ b2,
    void* __restrict__ C1, float* __restrict__ C2, const int N,
    ushort_t* smem) {
  const int tid = threadIdx.x;
  const int m0 = by * 96;
  const int n0 = bx * 128;
  const int wv = tid >> 6, lane = tid & 63;
  const int wm = wv >> 1, wn = wv & 1;
  const int l16 = lane & 15, quad = lane >> 4;
  const int l8 = l16 & 7;

  // ---- stage B once: 4096 chunks (128 rows x 32), 16 per thread ----
#pragma unroll
  for (int it = 0; it < 16; ++it) {
    const int c = tid + it * 256;
    const int row = c >> 5, kc = c & 31;
    const int grow = n0 + row;
    const float* bsrc;
    int r2;
    if (grow < bsplit) {
      bsrc = B1;
      r2 = grow;
    } else {
      bsrc = B2;
      r2 = grow - bsplit;
      const int rmax = N - bsplit - 1;
      if (r2 > rmax) r2 = rmax;  // clamp: garbage cols, stores guarded
    }
    const float* src = bsrc + (size_t)r2 * 256 + kc * 8;
    const float4 x0 = *(const float4*)src;
    const float4 x1 = *(const float4*)(src + 4);
    const short8 v = cvt8(x0, x1);
    *(short8*)&smem[(row * 32 + (kc ^ (row & 7))) * 8] = v;
  }
  __syncthreads();  // ONLY barrier before the epilogue

  // ---- A fragment base pointers ----
  const float* pA[3];
  const float* pA2[3];
  const ushort_t* pAb[3];
#pragma unroll
  for (int mi = 0; mi < 3; ++mi) {
    const int rr = m0 + wm * 48 + mi * 16 + l16;
    if (ASRC == 0) {
      pAb[mi] = Ab + (size_t)rr * 256 + quad * 8;
    } else {
      pA[mi] = A1 + (size_t)rr * 256 + quad * 8;
      if (ASRC == 2) pA2[mi] = A2 + (size_t)rr * 256 + quad * 8;
    }
  }
  // B LDS row bases (ushort units); row&7 == l8 for all ni
  int brow[4];
#pragma unroll
  for (int ni = 0; ni < 4; ++ni) brow[ni] = (wn * 64 + ni * 16 + l16) * 256;

  floatx4 acc[3][4];
#pragma unroll
  for (int i = 0; i < 3; ++i)
#pragma unroll
    for (int j = 0; j < 4; ++j) acc[i][j] = (floatx4)(0.f);

  // ---- barrier-free K-loop: 8 x k32 steps ----
#pragma unroll
  for (int k32 = 0; k32 < 8; ++k32) {
    short8 a[3], b[4];
#pragma unroll
    for (int mi = 0; mi < 3; ++mi) {
      if (ASRC == 0) {
        a[mi] = *(const short8*)(pAb[mi] + k32 * 32);
      } else {
        float4 x0 = *(const float4*)(pA[mi] + k32 * 32);
        float4 x1 = *(const float4*)(pA[mi] + k32 * 32 + 4);
        if (ASRC == 2) {
          x0 = add4(x0, *(const float4*)(pA2[mi] + k32 * 32));
          x1 = add4(x1, *(const float4*)(pA2[mi] + k32 * 32 + 4));
        }
        a[mi] = cvt8(x0, x1);
      }
    }
#pragma unroll
    for (int ni = 0; ni < 4; ++ni) {
      const int slot = ((k32 << 2) | quad) ^ l8;
      b[ni] = *(const short8*)&smem[brow[ni] + slot * 8];
    }
#pragma unroll
    for (int mi = 0; mi < 3; ++mi)
#pragma unroll
      for (int ni = 0; ni < 4; ++ni)
        acc[mi][ni] = __builtin_amdgcn_mfma_f32_16x16x32_bf16(a[mi], b[ni], acc[mi][ni], 0, 0, 0);
  }

  if (MODE == 0) {
    float* C = (float*)C1;
#pragma unroll
    for (int ni = 0; ni < 4; ++ni) {
      const int col = n0 + wn * 64 + ni * 16 + l16;
      const float bia = b1[col];
#pragma unroll
      for (int mi = 0; mi < 3; ++mi) {
        const int rr = m0 + wm * 48 + mi * 16 + quad * 4;
#pragma unroll
        for (int r = 0; r < 4; ++r)
          C[(size_t)(rr + r) * N + col] = acc[mi][ni][r] + bia;
      }
    }
  } else if (MODE == 1) {
    ushort_t* C = (ushort_t*)C1;
#pragma unroll
    for (int ni = 0; ni < 4; ++ni) {
      const int col = n0 + wn * 64 + ni * 16 + l16;
      const float bia = b1[col];
      const int h = col >> 5, ch = col & 31;
#pragma unroll
      for (int mi = 0; mi < 3; ++mi) {
        const int rr = m0 + wm * 48 + mi * 16 + quad * 4;
#pragma unroll
        for (int r = 0; r < 4; ++r)
          C[((size_t)h * QSEQ + rr + r) * 32 + ch] = f2bf(acc[mi][ni][r] + bia);
      }
    }
  } else {
    // MODE 2: cols [0,96) -> LDS logits (only bx==0 has them), then softmax;
    //         cols [96,288) -> C2 fp32 [Q,192]
    __syncthreads();  // all waves done reading Bs before smem reuse
    float* smf = (float*)smem;  // 96x96 fp32 = 36864 B
#pragma unroll
    for (int ni = 0; ni < 4; ++ni) {
      const int col = n0 + wn * 64 + ni * 16 + l16;
      if (col < 96) {
        const float bia = b1[col];
#pragma unroll
        for (int mi = 0; mi < 3; ++mi) {
          const int lr = wm * 48 + mi * 16 + quad * 4;
#pragma unroll
          for (int r = 0; r < 4; ++r)
            smf[(lr + r) * 96 + col] = acc[mi][ni][r] + bia;
        }
      } else if (col < 288) {
        const float bia = b2[col - 96];
#pragma unroll
        for (int mi = 0; mi < 3; ++mi) {
          const int rr = m0 + wm * 48 + mi * 16 + quad * 4;
#pragma unroll
          for (int r = 0; r < 4; ++r)
            C2[(size_t)(rr + r) * 192 + (col - 96)] = acc[mi][ni][r] + bia;
        }
      }
    }
    __syncthreads();
    if (bx == 0) {
      float* C = (float*)C1;
#pragma unroll
      for (int p = 0; p < 3; ++p) {
        const int task = tid + p * 256;  // 768 = 96 rows x 8 heads
        const int row = task >> 3, hh = task & 7;
        float v[12];
        float mx = -1e30f;
#pragma unroll
        for (int i = 0; i < 12; ++i) {
          v[i] = smf[row * 96 + hh * 12 + i];
          mx = fmaxf(mx, v[i]);
        }
        float s = 0.f;
#pragma unroll
        for (int i = 0; i < 12; ++i) {
          v[i] = __expf(v[i] - mx);
          s += v[i];
        }
        const float inv = 1.f / s;
        float4 o[3];
#pragma unroll
        for (int i = 0; i < 3; ++i) {
          o[i].x = v[i * 4 + 0] * inv;
          o[i].y = v[i * 4 + 1] * inv;
          o[i].z = v[i * 4 + 2] * inv;
          o[i].w = v[i * 4 + 3] * inv;
        }
        float4* dst = (float4*)&C[(size_t)(m0 + row) * 96 + hh * 12];
        dst[0] = o[0];
        dst[1] = o[1];
        dst[2] = o[2];
      }
    }
  }
}

// ---------------------------------------------------------------------------
// ONE dispatch for both independent pre-sampler GEMMs, flat grid 1750 with
// bijective XCD swizzle (1750 = 8*218+6): each XCD gets a contiguous work
// range -> A tiles read by one XCD only; work<700 = value GEMM (2bx x 350by),
// else offsets GEMM (3bx x 350by).
// ---------------------------------------------------------------------------
__global__ __launch_bounds__(256, 2) void pre_gemms(
    const float* __restrict__ ehs, const float* __restrict__ hidden,
    const float* __restrict__ pos,
    const float* __restrict__ Wv, const float* __restrict__ bv,
    const float* __restrict__ Wa, const float* __restrict__ ba,
    const float* __restrict__ Ws, const float* __restrict__ bs,
    ushort_t* __restrict__ value, float* __restrict__ attn,
    float* __restrict__ sp) {
  extern __shared__ ushort_t smem[];
  const int bid = blockIdx.x;
  const int xcd = bid & 7, idx = bid >> 3;
  const int work = (xcd < 6 ? xcd * 219 : 1314 + (xcd - 6) * 218) + idx;
  if (work < 700)
    gemm_body<1, 1>(work & 1, work >> 1, ehs, nullptr, nullptr,
                    Wv, Wv, 1 << 30, bv, nullptr, value, nullptr, 256, smem);
  else {
    const int w2 = work - 700;
    gemm_body<2, 2>(w2 % 3, w2 / 3, hidden, pos, nullptr,
                    Wa, Ws, 96, ba, bs, attn, sp, 288, smem);
  }
}

// ---------------------------------------------------------------------------
// out = sampled(bf16) @ Wo^T + bo -> fp32, flat grid 700 (= 8*87+4, swizzled)
// ---------------------------------------------------------------------------
__global__ __launch_bounds__(256, 2) void out_gemm(
    const ushort_t* __restrict__ samp, const float* __restrict__ Wo,
    const float* __restrict__ bo, float* __restrict__ out) {
  extern __shared__ ushort_t smem[];
  const int bid = blockIdx.x;
  const int xcd = bid & 7, idx = bid >> 3;
  const int work = (xcd < 4 ? xcd * 88 : 352 + (xcd - 4) * 87) + idx;
  gemm_body<0, 0>(work & 1, work >> 1, nullptr, nullptr, samp,
                  Wo, Wo, 1 << 30, bo, nullptr, out, nullptr, 256, smem);
}

// ---------------------------------------------------------------------------
// Sampling + aggregation (round 7 version, unchanged): two-phase structure,
// block = 32 q x ONE head (grid 1050*8, h = blockIdx.x & 7) so each XCD's
// L2 stays on a single 2.15MB head plane.
// ---------------------------------------------------------------------------
__global__ __launch_bounds__(256) void msda_sample_kernel(
    const ushort_t* __restrict__ value,  // [8][QSEQ][32] bf16
    const float* __restrict__ sp,        // [Q, 192]
    const float* __restrict__ attn,      // [Q, 96]
    const float* __restrict__ refp,      // [Q, 3, 2]
    ushort_t* __restrict__ outp) {       // [Q, 256] bf16
  __shared__ unsigned wtab[32 * 100];  // 12.8 KB
  const int tid = threadIdx.x;
  const int h = blockIdx.x & 7;            // XCD-affine head
  const int qbase = (blockIdx.x >> 3) * 32;

  // ---- phase 1: weights + tap offsets, full lane efficiency ----
#pragma unroll
  for (int pass = 0; pass < 2; ++pass) {
    const int it = tid + pass * 256;
    if (it < 384) {
      const int tq = it / 12;        // q within block
      const int pt = it - tq * 12;
      const int q = qbase + tq;
      const int lvl = pt >> 2;
      const int S = lvl == 0 ? 160 : (lvl == 1 ? 80 : 40);
      const int base = lvl == 0 ? 0 : (lvl == 1 ? 25600 : 32000);

      const float a = attn[q * 96 + h * 12 + pt];
      const float2 off = *(const float2*)&sp[q * 192 + h * 24 + pt * 2];
      const float2 rp = *(const float2*)&refp[q * 6 + lvl * 2];

      const float x = fmaf(rp.x, (float)S, off.x) - 0.5f;
      const float y = fmaf(rp.y, (float)S, off.y) - 0.5f;
      const float xf = floorf(x), yf = floorf(y);
      const int x0 = (int)xf, y0 = (int)yf;
      const float wx1 = x - xf, wy1 = y - yf;

      const float wx0z = (x0 >= 0 && x0 < S) ? 1.f - wx1 : 0.f;
      const float wx1z = (x0 + 1 >= 0 && x0 + 1 < S) ? wx1 : 0.f;
      const float wy0z = (y0 >= 0 && y0 < S) ? 1.f - wy1 : 0.f;
      const float wy1z = (y0 + 1 >= 0 && y0 + 1 < S) ? wy1 : 0.f;

      const int x0c = min(max(x0, 0), S - 1);
      const int x1c = min(max(x0 + 1, 0), S - 1);
      const int y0c = min(max(y0, 0), S - 1);
      const int y1c = min(max(y0 + 1, 0), S - 1);

      const int r0 = base + y0c * S, r1 = base + y1c * S;
      uint4 e0, e1;
      e0.x = __float_as_uint(a * wx0z * wy0z);
      e0.y = (unsigned)(r0 + x0c) << 6;
      e0.z = __float_as_uint(a * wx1z * wy0z);
      e0.w = (unsigned)(r0 + x1c) << 6;
      e1.x = __float_as_uint(a * wx0z * wy1z);
      e1.y = (unsigned)(r1 + x0c) << 6;
      e1.z = __float_as_uint(a * wx1z * wy1z);
      e1.w = (unsigned)(r1 + x1c) << 6;
      unsigned* dst = &wtab[tq * 100 + pt * 8];
      *(uint4*)dst = e0;
      *(uint4*)(dst + 4) = e1;
    }
  }
  __syncthreads();

  // ---- phase 2: per-lane serial accumulation over 48 rows ----
  const int wv = tid >> 6;             // wave -> q octet
  const int qi = (tid >> 3) & 7;       // q within octet
  const int c = tid & 7;               // channel group (4 ch)
  const int tq = wv * 8 + qi;
  const int q = qbase + tq;
  const unsigned* wt = &wtab[tq * 100];
  const char* vbase = (const char*)value + ((size_t)h * QSEQ) * 64 + c * 8;

  float f0 = 0.f, f1 = 0.f, f2 = 0.f, f3 = 0.f;
#pragma unroll
  for (int r = 0; r < 48; ++r) {
    const uint2 e = *(const uint2*)&wt[r * 2];  // ds_read_b64, imm offset
    const float w = __uint_as_float(e.x);
    const uint2 v = *(const uint2*)(vbase + e.y);
    f0 = fmaf(__uint_as_float(v.x << 16), w, f0);
    f1 = fmaf(__uint_as_float(v.x & 0xFFFF0000u), w, f1);
    f2 = fmaf(__uint_as_float(v.y << 16), w, f2);
    f3 = fmaf(__uint_as_float(v.y & 0xFFFF0000u), w, f3);
  }

  ushort_t t[4] = {f2bf(f0), f2bf(f1), f2bf(f2), f2bf(f3)};
  *(uint2*)&outp[(size_t)q * 256 + h * 32 + c * 4] = *(const uint2*)t;
}

extern "C" void kernel_launch(void* const* d_in, const int* in_sizes, int n_in,
                              void* d_out, int out_size, void* d_ws, size_t ws_size,
                              hipStream_t stream) {
  const float* hidden = (const float*)d_in[0];
  const float* ehs    = (const float*)d_in[1];
  const float* pos    = (const float*)d_in[2];
  const float* refp   = (const float*)d_in[3];
  const float* Wv = (const float*)d_in[4];
  const float* bv = (const float*)d_in[5];
  const float* Ws = (const float*)d_in[6];
  const float* bs = (const float*)d_in[7];
  const float* Wa = (const float*)d_in[8];
  const float* ba = (const float*)d_in[9];
  const float* Wo = (const float*)d_in[10];
  const float* bo = (const float*)d_in[11];

  float* out  = (float*)d_out;             // [Q, 256]
  float* attn = out + (size_t)QSEQ * 256;  // [Q, 96]

  char* ws = (char*)d_ws;
  ushort_t* ws_value = (ushort_t*)ws;                  // [8][Q][32] bf16
  ushort_t* ws_outp  = ws_value + (size_t)QSEQ * 256;  // [Q,256] bf16 sampled
  float* ws_sp = (float*)(ws_outp + (size_t)QSEQ * 256);  // [Q,192] fp32

  dim3 blk(256);

  // 1. both pre-sampler GEMMs in ONE dispatch (flat grid, XCD-swizzled)
  pre_gemms<<<dim3(1750), blk, 65536, stream>>>(
      ehs, hidden, pos, Wv, bv, Wa, ba, Ws, bs, ws_value, attn, ws_sp);
  // 2. sampling (block = 32 q x 1 head, two-phase, XCD-affine heads)
  msda_sample_kernel<<<dim3((QSEQ / 32) * 8), blk, 0, stream>>>(
      ws_value, ws_sp, attn, refp, ws_outp);
  // 3. output projection (flat grid 700, XCD-swizzled)
  out_gemm<<<dim3(700), blk, 65536, stream>>>(ws_outp, Wo, bo, out);
}

// Round 5
// 269.156 us; speedup vs baseline: 1.1970x; 1.1970x over previous
//
#include <hip/hip_runtime.h>
#include <math.h>

#define QSEQ 33600

typedef __attribute__((ext_vector_type(8))) short short8;
typedef __attribute__((ext_vector_type(4))) float floatx4;
typedef unsigned short ushort_t;

static __device__ __forceinline__ ushort_t f2bf(float f) {
  unsigned u = __float_as_uint(f);
  return (ushort_t)((u + 0x7FFF + ((u >> 16) & 1)) >> 16);
}

// packed f32x2 -> bf16x2 (RNE, same rounding as f2bf), single VALU op
static __device__ __forceinline__ unsigned pk2bf(float lo, float hi) {
  unsigned r;
  asm("v_cvt_pk_bf16_f32 %0, %1, %2" : "=v"(r) : "v"(lo), "v"(hi));
  return r;
}

static __device__ __forceinline__ short8 cvt8(const float4 x0, const float4 x1) {
  union { unsigned u[4]; short8 s; } r;
  r.u[0] = pk2bf(x0.x, x0.y);
  r.u[1] = pk2bf(x0.z, x0.w);
  r.u[2] = pk2bf(x1.x, x1.y);
  r.u[3] = pk2bf(x1.z, x1.w);
  return r.s;
}

static __device__ __forceinline__ float4 add4(float4 a, const float4 b) {
  a.x += b.x; a.y += b.y; a.z += b.z; a.w += b.w;
  return a;
}

// async global->LDS, 16B per lane; lds dest = wave-uniform base + lane*16
static __device__ __forceinline__ void gload_lds16(const void* g, void* l) {
  __builtin_amdgcn_global_load_lds((__attribute__((address_space(1))) void*)g,
                                   (__attribute__((address_space(3))) void*)l, 16, 0, 0);
}

// ---------------------------------------------------------------------------
// MFMA GEMM body (round 10 = round-2 proven single-buffer structure + pk-cvt).
// BM=96 (33600 = 350*96), BN=128, BK=64, K=256.
// 256 thr = 4 waves (2x2), wave tile 48x64 (3x4 frags of 16x16x32 bf16).
// LDS: As 96x64 bf16 | Bs 128x64 bf16, chunk-XOR swizzle (slot (row,s) holds
// global 16B-chunk s^(row&7)).
// Structure note: r3 double-buffer and r4 barrier-free both failed to beat
// this (compiler defeats source-level pipelining; r4 starved ILP at 60 VGPR).
// The win that survives from r4 is the XCD-bijective grid swizzle (callers).
// ASRC: 0 = A bf16 via global_load_lds; 1 = A fp32 cvt; 2 = fp32 A1+A2 add.
// MODE: 0 = fp32 C1[M,N]; 1 = bf16 head-major [col>>5][row][col&31];
//       2 = N=288 merged: cols<96 logits -> fused softmax -> C1 [Q,96] fp32,
//           cols [96,288) -> C2 [Q,192] fp32 (+b2).
// ---------------------------------------------------------------------------
template <int ASRC, int MODE>
static __device__ __forceinline__ void gemm_body(
    const int bx, const int by,
    const float* __restrict__ A1, const float* __restrict__ A2,
    const ushort_t* __restrict__ Ab,
    const float* __restrict__ B1, const float* __restrict__ B2, const int bsplit,
    const float* __restrict__ b1, const float* __restrict__ b2,
    void* __restrict__ C1, float* __restrict__ C2, const int N,
    ushort_t* smem) {
  ushort_t* As = smem;         // 6144 ushorts
  ushort_t* Bs = smem + 6144;  // 8192 ushorts

  const int tid = threadIdx.x;
  const int m0 = by * 96;
  const int n0 = bx * 128;
  const int wv = tid >> 6, lane = tid & 63;
  const int wm = wv >> 1, wn = wv & 1;
  const int l16 = lane & 15, quad = lane >> 4;
  const int l8 = l16 & 7;

  // --- A staging descriptors: 768 chunks (96 rows x 8), 3 per thread ---
  const float* gAf[3];
  const float* gAf2[3];
  const ushort_t* gAb[3];
  ushort_t* lA[3];
#pragma unroll
  for (int i = 0; i < 3; ++i) {
    const int c = tid + i * 256;
    const int row = c >> 3, s = c & 7;
    if (ASRC == 0) {
      gAb[i] = Ab + (size_t)(m0 + row) * 256 + ((s ^ (row & 7)) * 8);
      lA[i] = As + (wv * 64 + i * 256) * 8;  // wave-uniform base, lane-linear
    } else {
      gAf[i] = A1 + (size_t)(m0 + row) * 256 + s * 8;
      if (ASRC == 2) gAf2[i] = A2 + (size_t)(m0 + row) * 256 + s * 8;
      lA[i] = As + row * 64 + (s ^ (row & 7)) * 8;
    }
  }
  // --- B staging: 1024 chunks (128 rows x 8), 4 per thread, fp32 src ---
  const float* gBf[4];
  ushort_t* lBf[4];
#pragma unroll
  for (int j = 0; j < 4; ++j) {
    const int c = tid + j * 256;
    const int row = c >> 3, s = c & 7;
    const int grow = n0 + row;
    const float* bsrc;
    int r2;
    if (grow < bsplit) {
      bsrc = B1;
      r2 = grow;
    } else {
      bsrc = B2;
      r2 = grow - bsplit;
      const int rmax = N - bsplit - 1;
      if (r2 > rmax) r2 = rmax;  // clamp: garbage cols, stores guarded
    }
    gBf[j] = bsrc + (size_t)r2 * 256 + s * 8;
    lBf[j] = Bs + row * 64 + (s ^ (row & 7)) * 8;
  }

  floatx4 acc[3][4];
#pragma unroll
  for (int i = 0; i < 3; ++i)
#pragma unroll
    for (int j = 0; j < 4; ++j) acc[i][j] = (floatx4)(0.f);

  for (int k0 = 0; k0 < 256; k0 += 64) {
    // ---- stage A ----
    if (ASRC == 0) {
#pragma unroll
      for (int i = 0; i < 3; ++i) gload_lds16(gAb[i] + k0, lA[i]);
    } else {
#pragma unroll
      for (int i = 0; i < 3; ++i) {
        float4 x0 = *(const float4*)(gAf[i] + k0);
        float4 x1 = *(const float4*)(gAf[i] + k0 + 4);
        if (ASRC == 2) {
          x0 = add4(x0, *(const float4*)(gAf2[i] + k0));
          x1 = add4(x1, *(const float4*)(gAf2[i] + k0 + 4));
        }
        *(short8*)lA[i] = cvt8(x0, x1);
      }
    }
    // ---- stage B (fp32 -> bf16 inline, pk-cvt) ----
#pragma unroll
    for (int j = 0; j < 4; ++j) {
      const float4 x0 = *(const float4*)(gBf[j] + k0);
      const float4 x1 = *(const float4*)(gBf[j] + k0 + 4);
      *(short8*)lBf[j] = cvt8(x0, x1);
    }
    __syncthreads();

#pragma unroll
    for (int k32 = 0; k32 < 2; ++k32) {
      const int cx = ((k32 * 4 + quad) ^ l8) * 8;
      short8 a[3], b[4];
#pragma unroll
      for (int mi = 0; mi < 3; ++mi)
        a[mi] = *(const short8*)&As[(wm * 48 + mi * 16 + l16) * 64 + cx];
#pragma unroll
      for (int ni = 0; ni < 4; ++ni)
        b[ni] = *(const short8*)&Bs[(wn * 64 + ni * 16 + l16) * 64 + cx];
#pragma unroll
      for (int mi = 0; mi < 3; ++mi)
#pragma unroll
        for (int ni = 0; ni < 4; ++ni)
          acc[mi][ni] = __builtin_amdgcn_mfma_f32_16x16x32_bf16(a[mi], b[ni], acc[mi][ni], 0, 0, 0);
    }
    __syncthreads();
  }

  if (MODE == 0) {
    float* C = (float*)C1;
#pragma unroll
    for (int ni = 0; ni < 4; ++ni) {
      const int col = n0 + wn * 64 + ni * 16 + l16;
      const float bia = b1[col];
#pragma unroll
      for (int mi = 0; mi < 3; ++mi) {
        const int rr = m0 + wm * 48 + mi * 16 + quad * 4;
#pragma unroll
        for (int r = 0; r < 4; ++r)
          C[(size_t)(rr + r) * N + col] = acc[mi][ni][r] + bia;
      }
    }
  } else if (MODE == 1) {
    ushort_t* C = (ushort_t*)C1;
#pragma unroll
    for (int ni = 0; ni < 4; ++ni) {
      const int col = n0 + wn * 64 + ni * 16 + l16;
      const float bia = b1[col];
      const int h = col >> 5, ch = col & 31;
#pragma unroll
      for (int mi = 0; mi < 3; ++mi) {
        const int rr = m0 + wm * 48 + mi * 16 + quad * 4;
#pragma unroll
        for (int r = 0; r < 4; ++r)
          C[((size_t)h * QSEQ + rr + r) * 32 + ch] = f2bf(acc[mi][ni][r] + bia);
      }
    }
  } else {
    // MODE 2: cols [0,96) -> LDS logits (only bx==0 has them), then softmax;
    //         cols [96,288) -> C2 fp32 [Q,192]
    float* smf = (float*)smem;  // 96x96 fp32, reuses As/Bs area (36864 B)
#pragma unroll
    for (int ni = 0; ni < 4; ++ni) {
      const int col = n0 + wn * 64 + ni * 16 + l16;
      if (col < 96) {
        const float bia = b1[col];
#pragma unroll
        for (int mi = 0; mi < 3; ++mi) {
          const int lr = wm * 48 + mi * 16 + quad * 4;
#pragma unroll
          for (int r = 0; r < 4; ++r)
            smf[(lr + r) * 96 + col] = acc[mi][ni][r] + bia;
        }
      } else if (col < 288) {
        const float bia = b2[col - 96];
#pragma unroll
        for (int mi = 0; mi < 3; ++mi) {
          const int rr = m0 + wm * 48 + mi * 16 + quad * 4;
#pragma unroll
          for (int r = 0; r < 4; ++r)
            C2[(size_t)(rr + r) * 192 + (col - 96)] = acc[mi][ni][r] + bia;
        }
      }
    }
    __syncthreads();
    if (bx == 0) {
      float* C = (float*)C1;
#pragma unroll
      for (int p = 0; p < 3; ++p) {
        const int task = tid + p * 256;  // 768 = 96 rows x 8 heads
        const int row = task >> 3, hh = task & 7;
        float v[12];
        float mx = -1e30f;
#pragma unroll
        for (int i = 0; i < 12; ++i) {
          v[i] = smf[row * 96 + hh * 12 + i];
          mx = fmaxf(mx, v[i]);
        }
        float s = 0.f;
#pragma unroll
        for (int i = 0; i < 12; ++i) {
          v[i] = __expf(v[i] - mx);
          s += v[i];
        }
        const float inv = 1.f / s;
        float4 o[3];
#pragma unroll
        for (int i = 0; i < 3; ++i) {
          o[i].x = v[i * 4 + 0] * inv;
          o[i].y = v[i * 4 + 1] * inv;
          o[i].z = v[i * 4 + 2] * inv;
          o[i].w = v[i * 4 + 3] * inv;
        }
        float4* dst = (float4*)&C[(size_t)(m0 + row) * 96 + hh * 12];
        dst[0] = o[0];
        dst[1] = o[1];
        dst[2] = o[2];
      }
    }
  }
}

// ---------------------------------------------------------------------------
// ONE dispatch for both independent pre-sampler GEMMs, flat grid 1750 with
// bijective XCD swizzle (1750 = 6*219 + 2*218): each XCD owns a contiguous
// work range -> bx-neighbors sharing an A-panel run on the same XCD (r4:
// FETCH 140 -> 54 MB). work<700 = value GEMM (2bx x 350by), else offsets
// GEMM (3bx x 350by), bx-major so same-by blocks are adjacent.
// ---------------------------------------------------------------------------
__global__ __launch_bounds__(256) void pre_gemms(
    const float* __restrict__ ehs, const float* __restrict__ hidden,
    const float* __restrict__ pos,
    const float* __restrict__ Wv, const float* __restrict__ bv,
    const float* __restrict__ Wa, const float* __restrict__ ba,
    const float* __restrict__ Ws, const float* __restrict__ bs,
    ushort_t* __restrict__ value, float* __restrict__ attn,
    float* __restrict__ sp) {
  extern __shared__ ushort_t smem[];
  const int bid = blockIdx.x;
  const int xcd = bid & 7, idx = bid >> 3;
  const int work = (xcd < 6 ? xcd * 219 : 1314 + (xcd - 6) * 218) + idx;
  if (work < 700)
    gemm_body<1, 1>(work & 1, work >> 1, ehs, nullptr, nullptr,
                    Wv, Wv, 1 << 30, bv, nullptr, value, nullptr, 256, smem);
  else {
    const int w2 = work - 700;
    gemm_body<2, 2>(w2 % 3, w2 / 3, hidden, pos, nullptr,
                    Wa, Ws, 96, ba, bs, attn, sp, 288, smem);
  }
}

// ---------------------------------------------------------------------------
// out = sampled(bf16) @ Wo^T + bo -> fp32, flat grid 700 (= 4*88 + 4*87,
// XCD-bijective swizzle)
// ---------------------------------------------------------------------------
__global__ __launch_bounds__(256) void out_gemm(
    const ushort_t* __restrict__ samp, const float* __restrict__ Wo,
    const float* __restrict__ bo, float* __restrict__ out) {
  extern __shared__ ushort_t smem[];
  const int bid = blockIdx.x;
  const int xcd = bid & 7, idx = bid >> 3;
  const int work = (xcd < 4 ? xcd * 88 : 352 + (xcd - 4) * 87) + idx;
  gemm_body<0, 0>(work & 1, work >> 1, nullptr, nullptr, samp,
                  Wo, Wo, 1 << 30, bo, nullptr, out, nullptr, 256, smem);
}

// ---------------------------------------------------------------------------
// Sampling + aggregation (round 7 version, unchanged): two-phase structure,
// block = 32 q x ONE head (grid 1050*8, h = blockIdx.x & 7) so each XCD's
// L2 stays on a single 2.15MB head plane.
// ---------------------------------------------------------------------------
__global__ __launch_bounds__(256) void msda_sample_kernel(
    const ushort_t* __restrict__ value,  // [8][QSEQ][32] bf16
    const float* __restrict__ sp,        // [Q, 192]
    const float* __restrict__ attn,      // [Q, 96]
    const float* __restrict__ refp,      // [Q, 3, 2]
    ushort_t* __restrict__ outp) {       // [Q, 256] bf16
  __shared__ unsigned wtab[32 * 100];  // 12.8 KB
  const int tid = threadIdx.x;
  const int h = blockIdx.x & 7;            // XCD-affine head
  const int qbase = (blockIdx.x >> 3) * 32;

  // ---- phase 1: weights + tap offsets, full lane efficiency ----
#pragma unroll
  for (int pass = 0; pass < 2; ++pass) {
    const int it = tid + pass * 256;
    if (it < 384) {
      const int tq = it / 12;        // q within block
      const int pt = it - tq * 12;
      const int q = qbase + tq;
      const int lvl = pt >> 2;
      const int S = lvl == 0 ? 160 : (lvl == 1 ? 80 : 40);
      const int base = lvl == 0 ? 0 : (lvl == 1 ? 25600 : 32000);

      const float a = attn[q * 96 + h * 12 + pt];
      const float2 off = *(const float2*)&sp[q * 192 + h * 24 + pt * 2];
      const float2 rp = *(const float2*)&refp[q * 6 + lvl * 2];

      const float x = fmaf(rp.x, (float)S, off.x) - 0.5f;
      const float y = fmaf(rp.y, (float)S, off.y) - 0.5f;
      const float xf = floorf(x), yf = floorf(y);
      const int x0 = (int)xf, y0 = (int)yf;
      const float wx1 = x - xf, wy1 = y - yf;

      const float wx0z = (x0 >= 0 && x0 < S) ? 1.f - wx1 : 0.f;
      const float wx1z = (x0 + 1 >= 0 && x0 + 1 < S) ? wx1 : 0.f;
      const float wy0z = (y0 >= 0 && y0 < S) ? 1.f - wy1 : 0.f;
      const float wy1z = (y0 + 1 >= 0 && y0 + 1 < S) ? wy1 : 0.f;

      const int x0c = min(max(x0, 0), S - 1);
      const int x1c = min(max(x0 + 1, 0), S - 1);
      const int y0c = min(max(y0, 0), S - 1);
      const int y1c = min(max(y0 + 1, 0), S - 1);

      const int r0 = base + y0c * S, r1 = base + y1c * S;
      uint4 e0, e1;
      e0.x = __float_as_uint(a * wx0z * wy0z);
      e0.y = (unsigned)(r0 + x0c) << 6;
      e0.z = __float_as_uint(a * wx1z * wy0z);
      e0.w = (unsigned)(r0 + x1c) << 6;
      e1.x = __float_as_uint(a * wx0z * wy1z);
      e1.y = (unsigned)(r1 + x0c) << 6;
      e1.z = __float_as_uint(a * wx1z * wy1z);
      e1.w = (unsigned)(r1 + x1c) << 6;
      unsigned* dst = &wtab[tq * 100 + pt * 8];
      *(uint4*)dst = e0;
      *(uint4*)(dst + 4) = e1;
    }
  }
  __syncthreads();

  // ---- phase 2: per-lane serial accumulation over 48 rows ----
  const int wv = tid >> 6;             // wave -> q octet
  const int qi = (tid >> 3) & 7;       // q within octet
  const int c = tid & 7;               // channel group (4 ch)
  const int tq = wv * 8 + qi;
  const int q = qbase + tq;
  const unsigned* wt = &wtab[tq * 100];
  const char* vbase = (const char*)value + ((size_t)h * QSEQ) * 64 + c * 8;

  float f0 = 0.f, f1 = 0.f, f2 = 0.f, f3 = 0.f;
#pragma unroll
  for (int r = 0; r < 48; ++r) {
    const uint2 e = *(const uint2*)&wt[r * 2];  // ds_read_b64, imm offset
    const float w = __uint_as_float(e.x);
    const uint2 v = *(const uint2*)(vbase + e.y);
    f0 = fmaf(__uint_as_float(v.x << 16), w, f0);
    f1 = fmaf(__uint_as_float(v.x & 0xFFFF0000u), w, f1);
    f2 = fmaf(__uint_as_float(v.y << 16), w, f2);
    f3 = fmaf(__uint_as_float(v.y & 0xFFFF0000u), w, f3);
  }

  ushort_t t[4] = {f2bf(f0), f2bf(f1), f2bf(f2), f2bf(f3)};
  *(uint2*)&outp[(size_t)q * 256 + h * 32 + c * 4] = *(const uint2*)t;
}

extern "C" void kernel_launch(void* const* d_in, const int* in_sizes, int n_in,
                              void* d_out, int out_size, void* d_ws, size_t ws_size,
                              hipStream_t stream) {
  const float* hidden = (const float*)d_in[0];
  const float* ehs    = (const float*)d_in[1];
  const float* pos    = (const float*)d_in[2];
  const float* refp   = (const float*)d_in[3];
  const float* Wv = (const float*)d_in[4];
  const float* bv = (const float*)d_in[5];
  const float* Ws = (const float*)d_in[6];
  const float* bs = (const float*)d_in[7];
  const float* Wa = (const float*)d_in[8];
  const float* ba = (const float*)d_in[9];
  const float* Wo = (const float*)d_in[10];
  const float* bo = (const float*)d_in[11];

  float* out  = (float*)d_out;             // [Q, 256]
  float* attn = out + (size_t)QSEQ * 256;  // [Q, 96]

  char* ws = (char*)d_ws;
  ushort_t* ws_value = (ushort_t*)ws;                  // [8][Q][32] bf16
  ushort_t* ws_outp  = ws_value + (size_t)QSEQ * 256;  // [Q,256] bf16 sampled
  float* ws_sp = (float*)(ws_outp + (size_t)QSEQ * 256);  // [Q,192] fp32

  dim3 blk(256);

  // 1. both pre-sampler GEMMs in ONE dispatch (flat grid, XCD-swizzled)
  pre_gemms<<<dim3(1750), blk, 36864, stream>>>(
      ehs, hidden, pos, Wv, bv, Wa, ba, Ws, bs, ws_value, attn, ws_sp);
  // 2. sampling (block = 32 q x 1 head, two-phase, XCD-affine heads)
  msda_sample_kernel<<<dim3((QSEQ / 32) * 8), blk, 0, stream>>>(
      ws_value, ws_sp, attn, refp, ws_outp);
  // 3. output projection (flat grid 700, XCD-swizzled)
  out_gemm<<<dim3(700), blk, 28672, stream>>>(ws_outp, Wo, bo, out);
}